// Round 2
// baseline (127.342 us; speedup 1.0000x reference)
//
#include <hip/hip_runtime.h>
#include <hip/hip_fp16.h>
#include <math.h>

#define N_NODE 50000
#define D_FEAT 128
#define N_EDGE 625000
#define SIM_THRESH 0.1f
// int8 screen: dot-error std ~3.2e-3; 0.02 margin is ~6 sigma.
// (fp8 screen fallback: std ~3.4e-3; same margin.)
#define SCREEN_LO 0.08f
// fp16 sim error std ~3.5e-5; 5e-4 band is ~14x margin.
#define BAND_EPS 5e-4f

typedef float v2f __attribute__((ext_vector_type(2)));
typedef int   v4i __attribute__((ext_vector_type(4)));
typedef float v4f __attribute__((ext_vector_type(4)));

#if __has_builtin(__builtin_amdgcn_sdot4)
#define USE_SDOT4 1
#else
#define USE_SDOT4 0
#endif

#if __has_builtin(__builtin_amdgcn_fdot2)
#define USE_FDOT2 1
typedef _Float16 h2v __attribute__((ext_vector_type(2)));
#else
#define USE_FDOT2 0
#endif

// ===========================================================================
// K1: per-node inv-norm; normalized fp16 value table + int8 (or fp8) screen
// table; zero row_sum/degree (ws poisoned 0xAA). 32 lanes/node.
// ===========================================================================
__global__ void prep_kernel(const float* __restrict__ feat,
                            float* __restrict__ inv_nrm,
                            __half* __restrict__ fn16,
                            unsigned int* __restrict__ qtab,
                            float* __restrict__ row_sum,
                            float* __restrict__ degree) {
    int g = blockIdx.x * blockDim.x + threadIdx.x;
    if (g < N_NODE) { row_sum[g] = 0.0f; degree[g] = 0.0f; }
    int node = g >> 5;
    int lane = g & 31;
    if (node >= N_NODE) return;
    float4 v = ((const float4*)(feat + (size_t)node * D_FEAT))[lane];
    float ss = v.x * v.x + v.y * v.y + v.z * v.z + v.w * v.w;
#pragma unroll
    for (int o = 16; o > 0; o >>= 1) ss += __shfl_xor(ss, o, 32);
    float inv = 1.0f / fmaxf(sqrtf(ss), 1e-12f);
    if (lane == 0) inv_nrm[node] = inv;
    float x0 = v.x * inv, x1 = v.y * inv, x2 = v.z * inv, x3 = v.w * inv;
    __half2 h0 = __floats2half2_rn(x0, x1);
    __half2 h1 = __floats2half2_rn(x2, x3);
    uint2 p;
    p.x = *(unsigned int*)&h0;
    p.y = *(unsigned int*)&h1;
    ((uint2*)(fn16 + (size_t)node * D_FEAT))[lane] = p;
#if USE_SDOT4
    // int8 symmetric quant: x in [-1,1] -> [-127,127], exact fit.
    int q0 = (int)rintf(x0 * 127.0f);
    int q1 = (int)rintf(x1 * 127.0f);
    int q2 = (int)rintf(x2 * 127.0f);
    int q3 = (int)rintf(x3 * 127.0f);
    unsigned int w = (unsigned int)(q0 & 0xff) | ((unsigned int)(q1 & 0xff) << 8) |
                     ((unsigned int)(q2 & 0xff) << 16) | ((unsigned int)(q3 & 0xff) << 24);
#else
    int wi = __builtin_amdgcn_cvt_pk_fp8_f32(x0, x1, 0, false);
    wi = __builtin_amdgcn_cvt_pk_fp8_f32(x2, x3, wi, true);
    unsigned int w = (unsigned int)wi;
#endif
    qtab[(size_t)node * 32 + lane] = w;
}

// ===========================================================================
// K2: per-edge sim, 8 lanes/edge (8 edges per wave). Three-tier precision:
//   int8 sdot4 screen (uint4/lane) -> fp16 fdot2 value (sim8 > 0.08, ~18%)
//                                  -> fp32 exact (|sim16-0.1| < 5e-4, ~0.25%)
// ===========================================================================
__global__ __launch_bounds__(256)
void edge_sim8_kernel(const int* __restrict__ row,
                      const int* __restrict__ col,
                      const float* __restrict__ feat,
                      const float* __restrict__ inv_nrm,
                      const __half* __restrict__ fn16,
                      const unsigned int* __restrict__ qtab,
                      float* __restrict__ sim_out,
                      float* __restrict__ row_sum,
                      float* __restrict__ degree) {
    int g = blockIdx.x * blockDim.x + threadIdx.x;
    int edge = g >> 3;
    int lane = g & 7;
    if (edge >= N_EDGE) return;
    // streamed once: nontemporal so they don't evict the gather tables from L2
    int r = __builtin_nontemporal_load(row + edge);
    int c = __builtin_nontemporal_load(col + edge);

    // --- tier 1: low-precision screen, 16 B/lane per endpoint (one 128B line/row)
    uint4 aw = ((const uint4*)(qtab + (size_t)r * 32))[lane];
    uint4 bw = ((const uint4*)(qtab + (size_t)c * 32))[lane];
    float d;
#if USE_SDOT4
    {
        const unsigned int* awp = (const unsigned int*)&aw;
        const unsigned int* bwp = (const unsigned int*)&bw;
        int acc = 0;
#pragma unroll
        for (int i = 0; i < 4; i++)
            acc = __builtin_amdgcn_sdot4((int)awp[i], (int)bwp[i], acc, false);
#pragma unroll
        for (int o = 4; o > 0; o >>= 1) acc += __shfl_xor(acc, o, 8);
        d = (float)acc * (1.0f / 16129.0f);   // 1/127^2
    }
#else
    {
        const unsigned int* awp = (const unsigned int*)&aw;
        const unsigned int* bwp = (const unsigned int*)&bw;
        d = 0.0f;
#pragma unroll
        for (int i = 0; i < 4; i++) {
            v2f alo = __builtin_amdgcn_cvt_pk_f32_fp8((int)awp[i], false);
            v2f ahi = __builtin_amdgcn_cvt_pk_f32_fp8((int)awp[i], true);
            v2f blo = __builtin_amdgcn_cvt_pk_f32_fp8((int)bwp[i], false);
            v2f bhi = __builtin_amdgcn_cvt_pk_f32_fp8((int)bwp[i], true);
            d = fmaf(alo.x, blo.x, d); d = fmaf(alo.y, blo.y, d);
            d = fmaf(ahi.x, bhi.x, d); d = fmaf(ahi.y, bhi.y, d);
        }
#pragma unroll
        for (int o = 4; o > 0; o >>= 1) d += __shfl_xor(d, o, 8);
    }
#endif
    // xor butterfly leaves identical sum in all 8 lanes -> group-uniform branch

    float s = 0.0f;
    if (d > SCREEN_LO) {
        // --- tier 2: fp16 value, 32 B/lane per endpoint ---
        const float4* ar = (const float4*)(fn16 + (size_t)r * D_FEAT);
        const float4* br = (const float4*)(fn16 + (size_t)c * D_FEAT);
        float4 a0 = ar[lane], a1 = ar[lane + 8];
        float4 b0 = br[lane], b1 = br[lane + 8];
        float dh = 0.0f;
#if USE_FDOT2
        {
            const h2v* ah0 = (const h2v*)&a0;
            const h2v* bh0 = (const h2v*)&b0;
            const h2v* ah1 = (const h2v*)&a1;
            const h2v* bh1 = (const h2v*)&b1;
#pragma unroll
            for (int i = 0; i < 4; i++) {
                dh = __builtin_amdgcn_fdot2(ah0[i], bh0[i], dh, false);
                dh = __builtin_amdgcn_fdot2(ah1[i], bh1[i], dh, false);
            }
        }
#else
        {
            const __half2* ah0 = (const __half2*)&a0;
            const __half2* bh0 = (const __half2*)&b0;
            const __half2* ah1 = (const __half2*)&a1;
            const __half2* bh1 = (const __half2*)&b1;
#pragma unroll
            for (int i = 0; i < 4; i++) {
                float2 afv = __half22float2(ah0[i]);
                float2 bfv = __half22float2(bh0[i]);
                dh = fmaf(afv.x, bfv.x, dh);
                dh = fmaf(afv.y, bfv.y, dh);
                float2 afw = __half22float2(ah1[i]);
                float2 bfw = __half22float2(bh1[i]);
                dh = fmaf(afw.x, bfw.x, dh);
                dh = fmaf(afw.y, bfw.y, dh);
            }
        }
#endif
#pragma unroll
        for (int o = 4; o > 0; o >>= 1) dh += __shfl_xor(dh, o, 8);
        if (fabsf(dh - SIM_THRESH) < BAND_EPS) {
            // --- tier 3: exact fp32 (rare ~0.25%) ---
            const float4* fr = (const float4*)(feat + (size_t)r * D_FEAT);
            const float4* fc = (const float4*)(feat + (size_t)c * D_FEAT);
            float dd = 0.0f;
#pragma unroll
            for (int q = 0; q < 4; q++) {
                float4 av = fr[lane + q * 8];
                float4 bv = fc[lane + q * 8];
                dd += av.x * bv.x + av.y * bv.y + av.z * bv.z + av.w * bv.w;
            }
#pragma unroll
            for (int o = 4; o > 0; o >>= 1) dd += __shfl_xor(dd, o, 8);
            dh = dd * inv_nrm[r] * inv_nrm[c];
        }
        s = (dh < SIM_THRESH) ? 0.0f : dh;
    }
    if (lane == 0) {
        sim_out[edge] = s;
        if (s != 0.0f) {
            atomicAdd(&row_sum[r], s);
            atomicAdd(&degree[r], 1.0f);
        }
    }
}

// ===========================================================================
// K3: epilogue — normalize, diagonal lam, exp, gate blend, clamp.
// 4 edges/thread (N_EDGE % 4 == 0), vectorized nontemporal streams.
// NOTE: __builtin_nontemporal_* requires clang ext_vector types (v4i/v4f),
// NOT HIP_vector_type int4/float4 (compile error).
// ===========================================================================
__global__ void edge_out_kernel(const int* __restrict__ row,
                                const int* __restrict__ col,
                                const float* __restrict__ sim,
                                const float* __restrict__ row_sum,
                                const float* __restrict__ degree,
                                const float* __restrict__ ew,
                                const float* __restrict__ gate,
                                float* __restrict__ out) {
    int t = blockIdx.x * blockDim.x + threadIdx.x;
    if (t >= N_EDGE / 4) return;
    v4i r4 = __builtin_nontemporal_load((const v4i*)row + t);
    v4i c4 = __builtin_nontemporal_load((const v4i*)col + t);
    v4f s4 = __builtin_nontemporal_load((const v4f*)sim + t);
    v4f w4 = __builtin_nontemporal_load((const v4f*)ew + t);
    float gv = gate[0];
    float og = 1.0f - gv;
    v4f o4;
#pragma unroll
    for (int i = 0; i < 4; i++) {
        int   ri = r4[i];
        float rs = row_sum[ri];
        float att = s4[i] / ((rs > 0.0f) ? rs : 1.0f);
        if (ri == c4[i]) att += 1.0f / (degree[ri] + 1.0f);
        o4[i] = fmaxf(gv * w4[i] + og * expf(att), 0.0f);
    }
    __builtin_nontemporal_store(o4, (v4f*)out + t);
}

// ===========================================================================
// Fallback (pure fp32) if ws too small.
// ===========================================================================
__global__ void inv_norm_kernel(const float* __restrict__ feat,
                                float* __restrict__ inv_nrm,
                                float* __restrict__ row_sum,
                                float* __restrict__ degree) {
    int g = blockIdx.x * blockDim.x + threadIdx.x;
    if (g < N_NODE) { row_sum[g] = 0.0f; degree[g] = 0.0f; }
    int node = g >> 5;
    int lane = g & 31;
    if (node >= N_NODE) return;
    float4 v = ((const float4*)(feat + (size_t)node * D_FEAT))[lane];
    float ss = v.x * v.x + v.y * v.y + v.z * v.z + v.w * v.w;
#pragma unroll
    for (int o = 16; o > 0; o >>= 1) ss += __shfl_down(ss, o, 32);
    if (lane == 0) inv_nrm[node] = 1.0f / fmaxf(sqrtf(ss), 1e-12f);
}

__global__ void edge_sim_kernel(const int* __restrict__ row,
                                const int* __restrict__ col,
                                const float* __restrict__ feat,
                                const float* __restrict__ inv_nrm,
                                float* __restrict__ sim_out,
                                float* __restrict__ row_sum,
                                float* __restrict__ degree) {
    int g = blockIdx.x * blockDim.x + threadIdx.x;
    int edge = g >> 5;
    int lane = g & 31;
    if (edge >= N_EDGE) return;
    int r = row[edge];
    int c = col[edge];
    float4 a = ((const float4*)(feat + (size_t)r * D_FEAT))[lane];
    float4 b = ((const float4*)(feat + (size_t)c * D_FEAT))[lane];
    float d = a.x * b.x + a.y * b.y + a.z * b.z + a.w * b.w;
#pragma unroll
    for (int o = 16; o > 0; o >>= 1) d += __shfl_down(d, o, 32);
    if (lane == 0) {
        float s = d * inv_nrm[r] * inv_nrm[c];
        if (s < SIM_THRESH) s = 0.0f;
        sim_out[edge] = s;
        if (s != 0.0f) {
            atomicAdd(&row_sum[r], s);
            atomicAdd(&degree[r], 1.0f);
        }
    }
}

// ===========================================================================
// Launch — 3 dispatches. Journal constraints baked in:
//  - grid.sync costs ~600us on MI355X (R3): never fuse across the reduction.
//  - CSR/bucket permutation passes cost more than the <=24MB dedup they can
//    win (R5, R6): keep the edge order as-given.
//  - top-5 rocprof dispatches are all 268MB ws re-poison fills (~44us each,
//    ~76% HBM peak) — harness machinery, not addressable from the kernel.
// ===========================================================================
extern "C" void kernel_launch(void* const* d_in, const int* in_sizes, int n_in,
                              void* d_out, int out_size, void* d_ws, size_t ws_size,
                              hipStream_t stream) {
    const int*   edge_index = (const int*)d_in[0];   // [2, E]: row then col
    const float* ew         = (const float*)d_in[1];
    const float* feat       = (const float*)d_in[2];
    const float* gate       = (const float*)d_in[3];
    float*       out        = (float*)d_out;

    const int* row = edge_index;
    const int* col = edge_index + N_EDGE;

    // ws layout: row_sum[N] | degree[N] | inv_nrm[N] | sim[E]
    //            | fn16[N*128 halves] | qtab[N*32 uints]
    float* row_sum = (float*)d_ws;
    float* degree  = row_sum + N_NODE;
    float* inv_nrm = degree + N_NODE;
    float* sim     = inv_nrm + N_NODE;
    __half* fn16   = (__half*)(sim + N_EDGE);
    unsigned int* qtab = (unsigned int*)(fn16 + (size_t)N_NODE * D_FEAT);

    size_t need = (size_t)(3 * N_NODE + N_EDGE) * 4
                + (size_t)N_NODE * D_FEAT * 2
                + (size_t)N_NODE * D_FEAT;

    const int block = 256;

    if (ws_size >= need) {
        {
            long long threads = (long long)N_NODE * 32;
            prep_kernel<<<(int)((threads + block - 1) / block), block, 0, stream>>>(
                feat, inv_nrm, fn16, qtab, row_sum, degree);
        }
        {
            long long threads = (long long)N_EDGE * 8;
            edge_sim8_kernel<<<(int)((threads + block - 1) / block), block, 0, stream>>>(
                row, col, feat, inv_nrm, fn16, qtab, sim, row_sum, degree);
        }
        {
            int threads = N_EDGE / 4;
            edge_out_kernel<<<(threads + block - 1) / block, block, 0, stream>>>(
                row, col, sim, row_sum, degree, ew, gate, out);
        }
    } else {
        {
            long long threads = (long long)N_NODE * 32;
            inv_norm_kernel<<<(int)((threads + block - 1) / block), block, 0, stream>>>(
                feat, inv_nrm, row_sum, degree);
        }
        {
            long long threads = (long long)N_EDGE * 32;
            edge_sim_kernel<<<(int)((threads + block - 1) / block), block, 0, stream>>>(
                row, col, feat, inv_nrm, sim, row_sum, degree);
        }
        {
            int threads = N_EDGE / 4;
            edge_out_kernel<<<(threads + block - 1) / block, block, 0, stream>>>(
                row, col, sim, row_sum, degree, ew, gate, out);
        }
    }
}